// Round 2
// baseline (1774.317 us; speedup 1.0000x reference)
//
#include <hip/hip_runtime.h>
#include <math.h>

#define LDIM 2048
#define DDIM 128
#define BDIM 16
#define FDIM 100
#define TCONV 16
#define NBLK 16   // LDIM / 128

__device__ inline void ins3r(float w, int idx, float& v0, float& v1, float& v2,
                             int& i0, int& i1, int& i2) {
  if (w > v2) {
    if (w > v0) { v2=v1; i2=i1; v1=v0; i1=i0; v0=w; i0=idx; }
    else if (w > v1) { v2=v1; i2=i1; v1=w; i1=idx; }
    else { v2=w; i2=idx; }
  }
}

// Fused: W-tile (128x128) in registers + per-tile row/col {top3,sum,sumsq} partials.
// rowPart[(b*NBLK + mblk)*LDIM + c][8] = {v0,v1,v2,i0,i1,i2,sum,sq}  (idx bitcast)
// colPart[(b*NBLK + cblk)*LDIM + m][8]
__global__ __launch_bounds__(256) void gemm_fused(const float* __restrict__ ctx,
    const float* __restrict__ mn, float* __restrict__ rowPart,
    float* __restrict__ colPart) {
  __shared__ float smem[2 * 32 * 132];            // 33792 B; reused by col reduce
  float (*As)[132] = (float (*)[132])smem;        // [k][c] transposed
  float (*Bs)[132] = (float (*)[132])(smem + 32 * 132);
  const int b  = blockIdx.z;
  const int cb = blockIdx.y, mb = blockIdx.x;
  const int c0 = cb * 128,   m0 = mb * 128;
  const int tid = threadIdx.x;
  const int tx = tid & 15, ty = tid >> 4;
  const float4* A4 = (const float4*)(ctx + ((size_t)b*LDIM + c0)*DDIM);
  const float4* B4 = (const float4*)(mn  + ((size_t)b*LDIM + m0)*DDIM);

  float acc[8][8] = {};
  for (int t = 0; t < 4; t++) {                   // K chunks of 32
    __syncthreads();
    #pragma unroll
    for (int u = 0; u < 4; u++) {                 // 1024 float4 per matrix, 4/thread
      int e = tid + u*256;
      int r = e >> 3, kql = e & 7;
      float4 av = A4[(size_t)r*32 + t*8 + kql];
      float4 bv = B4[(size_t)r*32 + t*8 + kql];
      int kk = kql * 4;
      As[kk+0][r]=av.x; As[kk+1][r]=av.y; As[kk+2][r]=av.z; As[kk+3][r]=av.w;
      Bs[kk+0][r]=bv.x; Bs[kk+1][r]=bv.y; Bs[kk+2][r]=bv.z; Bs[kk+3][r]=bv.w;
    }
    __syncthreads();
    #pragma unroll 4
    for (int k = 0; k < 32; k++) {
      float a[8], bb[8];
      *(float4*)&a[0]  = *(const float4*)&As[k][ty*8];
      *(float4*)&a[4]  = *(const float4*)&As[k][ty*8+4];
      *(float4*)&bb[0] = *(const float4*)&Bs[k][tx*8];
      *(float4*)&bb[4] = *(const float4*)&Bs[k][tx*8+4];
      #pragma unroll
      for (int i = 0; i < 8; i++)
        #pragma unroll
        for (int j = 0; j < 8; j++)
          acc[i][j] += a[i] * bb[j];
    }
  }

  // ---- row partials: reduce over tx (shuffle, width 16) ----
  #pragma unroll 1
  for (int i = 0; i < 8; i++) {
    float v0=-3e38f, v1=-3e38f, v2=-3e38f; int i0=-1, i1=-1, i2=-1;
    float s = 0.f, q = 0.f;
    #pragma unroll
    for (int j = 0; j < 8; j++) {
      float w = acc[i][j]; s += w; q += w*w;
      ins3r(w, m0 + tx*8 + j, v0,v1,v2,i0,i1,i2);
    }
    #pragma unroll
    for (int m = 1; m < 16; m <<= 1) {
      float ov0=__shfl_xor(v0,m,16), ov1=__shfl_xor(v1,m,16), ov2=__shfl_xor(v2,m,16);
      int   oi0=__shfl_xor(i0,m,16), oi1=__shfl_xor(i1,m,16), oi2=__shfl_xor(i2,m,16);
      float os =__shfl_xor(s,m,16),  oq =__shfl_xor(q,m,16);
      s += os; q += oq;
      ins3r(ov0,oi0,v0,v1,v2,i0,i1,i2);
      ins3r(ov1,oi1,v0,v1,v2,i0,i1,i2);
      ins3r(ov2,oi2,v0,v1,v2,i0,i1,i2);
    }
    if (tx == 0) {
      float* p = rowPart + ((size_t)(b*NBLK + mb)*LDIM + c0 + ty*8 + i) * 8;
      float4 lo = {v0, v1, v2, __int_as_float(i0)};
      float4 hi = {__int_as_float(i1), __int_as_float(i2), s, q};
      *(float4*)p = lo; *(float4*)(p+4) = hi;
    }
  }

  // ---- col partials: in-wave reduce over ty%4, cross-wave via LDS ----
  __syncthreads();                                // done with As/Bs
  float* cbuf = smem;                             // [4 wave][16 tx][8 j][8] = 16 KB
  const int wave = tid >> 6;
  const int tyl  = (tid >> 4) & 3;
  #pragma unroll 1
  for (int j = 0; j < 8; j++) {
    float v0=-3e38f, v1=-3e38f, v2=-3e38f; int i0=-1, i1=-1, i2=-1;
    float s = 0.f, q = 0.f;
    #pragma unroll
    for (int i = 0; i < 8; i++) {
      float w = acc[i][j]; s += w; q += w*w;
      ins3r(w, c0 + ty*8 + i, v0,v1,v2,i0,i1,i2);
    }
    #pragma unroll
    for (int m = 16; m < 64; m <<= 1) {           // lanes ty^1, ty^2 (same tx)
      float ov0=__shfl_xor(v0,m), ov1=__shfl_xor(v1,m), ov2=__shfl_xor(v2,m);
      int   oi0=__shfl_xor(i0,m), oi1=__shfl_xor(i1,m), oi2=__shfl_xor(i2,m);
      float os =__shfl_xor(s,m),  oq =__shfl_xor(q,m);
      s += os; q += oq;
      ins3r(ov0,oi0,v0,v1,v2,i0,i1,i2);
      ins3r(ov1,oi1,v0,v1,v2,i0,i1,i2);
      ins3r(ov2,oi2,v0,v1,v2,i0,i1,i2);
    }
    if (tyl == 0) {
      float* p = cbuf + (((wave*16 + tx)*8 + j) * 8);
      float4 lo = {v0, v1, v2, __int_as_float(i0)};
      float4 hi = {__int_as_float(i1), __int_as_float(i2), s, q};
      *(float4*)p = lo; *(float4*)(p+4) = hi;
    }
  }
  __syncthreads();
  if (tid < 128) {                                // worker per (tx, j): merge 4 waves
    int txw = tid >> 3, j = tid & 7;
    float v0=-3e38f, v1=-3e38f, v2=-3e38f; int i0=-1, i1=-1, i2=-1;
    float s = 0.f, q = 0.f;
    #pragma unroll
    for (int w = 0; w < 4; w++) {
      float* p = cbuf + (((w*16 + txw)*8 + j) * 8);
      float4 lo = *(float4*)p, hi = *(float4*)(p+4);
      ins3r(lo.x, __float_as_int(lo.w), v0,v1,v2,i0,i1,i2);
      ins3r(lo.y, __float_as_int(hi.x), v0,v1,v2,i0,i1,i2);
      ins3r(lo.z, __float_as_int(hi.y), v0,v1,v2,i0,i1,i2);
      s += hi.z; q += hi.w;
    }
    float* p = colPart + ((size_t)(b*NBLK + cb)*LDIM + m0 + txw*8 + j) * 8;
    float4 lo = {v0, v1, v2, __int_as_float(i0)};
    float4 hi = {__int_as_float(i1), __int_as_float(i2), s, q};
    *(float4*)p = lo; *(float4*)(p+4) = hi;
  }
}

// Merge NBLK tile-partials per line -> normalized top-3 weights, indices, std.
__global__ __launch_bounds__(256) void reduce_stats(const float* __restrict__ part,
    float* __restrict__ w3, int* __restrict__ i3, float* __restrict__ sd) {
  int gid = blockIdx.x * 256 + threadIdx.x;       // over nb*LDIM lines
  int b = gid >> 11, r = gid & 2047;
  float v0=-3e38f, v1=-3e38f, v2=-3e38f; int i0=-1, i1=-1, i2=-1;
  float s = 0.f, q = 0.f;
  for (int blk = 0; blk < NBLK; blk++) {
    const float* p = part + ((size_t)(b*NBLK + blk)*LDIM + r) * 8;
    float4 lo = *(const float4*)p, hi = *(const float4*)(p+4);
    ins3r(lo.x, __float_as_int(lo.w), v0,v1,v2,i0,i1,i2);
    ins3r(lo.y, __float_as_int(hi.x), v0,v1,v2,i0,i1,i2);
    ins3r(lo.z, __float_as_int(hi.y), v0,v1,v2,i0,i1,i2);
    s += hi.z; q += hi.w;
  }
  float inv = 1.f / (v0 + v1 + v2);
  w3[(size_t)gid*3+0] = v0*inv; w3[(size_t)gid*3+1] = v1*inv; w3[(size_t)gid*3+2] = v2*inv;
  i3[(size_t)gid*3+0] = i0; i3[(size_t)gid*3+1] = i1; i3[(size_t)gid*3+2] = i2;
  float mean = s * (1.f/LDIM);
  float var  = q * (1.f/LDIM) - mean*mean;
  sd[gid] = sqrtf(fmaxf(var, 0.f));
}

// att_merge_c[m][d] += wk_c[c][m] * ctx[c][d]  -- 3 targets per row c (scatter).
__global__ __launch_bounds__(128) void scatter_att(const float* __restrict__ ctx,
    const float* __restrict__ rw, const int* __restrict__ ri,
    float* __restrict__ attC) {
  const int b = blockIdx.y, c = blockIdx.x, d = threadIdx.x;
  const size_t base = (size_t)b*LDIM + c;
  const float x = ctx[base*DDIM + d];
  #pragma unroll
  for (int t = 0; t < 3; t++) {
    float w = rw[base*3 + t];
    int m = ri[base*3 + t];
    atomicAdd(&attC[((size_t)b*LDIM + m)*DDIM + d], w*x);
  }
}

// outputs_c = |ctx - gather(col top-3 of main)| * row_std ; outputs_m = |main - attC| * col_std
__global__ __launch_bounds__(128) void make_outputs(const float* __restrict__ ctx,
    const float* __restrict__ mn, const float* __restrict__ attC,
    const float* __restrict__ rs, const float* __restrict__ cw,
    const int* __restrict__ ci, const float* __restrict__ cs,
    float* __restrict__ outC, float* __restrict__ outM) {
  const int b = blockIdx.y, i = blockIdx.x, d = threadIdx.x;
  const size_t base = (size_t)b*LDIM + i;
  float am = 0.f;
  #pragma unroll
  for (int t = 0; t < 3; t++)
    am += cw[base*3+t] * mn[((size_t)b*LDIM + ci[base*3+t])*DDIM + d];
  outC[base*DDIM + d] = fabsf(ctx[base*DDIM + d] - am) * rs[base];
  outM[base*DDIM + d] = fabsf(mn[base*DDIM + d] - attC[base*DDIM + d]) * cs[base];
}

// conv1d(KS=3, valid) + bias + relu + maxpool. z=0: outC->pool_c, z=1: outM->pool_m.
__global__ __launch_bounds__(128) void conv_pool(const float* __restrict__ XC,
    const float* __restrict__ XM, const float* __restrict__ wv,
    const float* __restrict__ bias, float* __restrict__ out) {
  const int b = blockIdx.y, z = blockIdx.z;
  const int t0 = blockIdx.x * TCONV;
  const float* X = (z == 0 ? XC : XM) + (size_t)b*LDIM*DDIM;
  __shared__ float Xs[TCONV+2][DDIM];
  const int tid = threadIdx.x;
  for (int e = tid; e < (TCONV+2)*DDIM; e += 128) {
    int tt = e >> 7, d = e & 127;
    int t = t0 + tt;
    Xs[tt][d] = (t < LDIM) ? X[(size_t)t*DDIM + d] : 0.f;
  }
  __syncthreads();
  const int f = tid;
  if (f < FDIM) {
    float y[TCONV];
    #pragma unroll
    for (int t = 0; t < TCONV; t++) y[t] = 0.f;
    for (int dq = 0; dq < DDIM/4; dq++) {
      float4 xq[TCONV+2];
      #pragma unroll
      for (int i = 0; i < TCONV+2; i++) xq[i] = *(const float4*)&Xs[i][dq*4];
      #pragma unroll
      for (int ks = 0; ks < 3; ks++) {
        float w0 = wv[(ks*DDIM + dq*4+0)*FDIM + f];
        float w1 = wv[(ks*DDIM + dq*4+1)*FDIM + f];
        float w2 = wv[(ks*DDIM + dq*4+2)*FDIM + f];
        float w3 = wv[(ks*DDIM + dq*4+3)*FDIM + f];
        #pragma unroll
        for (int t = 0; t < TCONV; t++)
          y[t] += xq[t+ks].x*w0 + xq[t+ks].y*w1 + xq[t+ks].z*w2 + xq[t+ks].w*w3;
      }
    }
    float bv = bias[f];
    float mx = 0.f;
    #pragma unroll
    for (int t = 0; t < TCONV; t++) {
      if (t0 + t < LDIM - 2) mx = fmaxf(mx, fmaxf(y[t] + bv, 0.f));
    }
    atomicMax((unsigned int*)&out[(size_t)b*(2*FDIM) + z*FDIM + f], __float_as_uint(mx));
  }
}

extern "C" void kernel_launch(void* const* d_in, const int* in_sizes, int n_in,
                              void* d_out, int out_size, void* d_ws, size_t ws_size,
                              hipStream_t stream) {
  const float* ctx   = (const float*)d_in[0];
  const float* mn    = (const float*)d_in[1];
  const float* wconv = (const float*)d_in[2];
  const float* bias  = (const float*)d_in[3];
  float* out = (float*)d_out;

  hipMemsetAsync(d_out, 0, sizeof(float)*(size_t)out_size, stream);

  // Per-batch ws floats: rowPart(16*2048*8) + colPart + 14*L stats + 3*L*D bufs
  const size_t PB_PART = (size_t)NBLK*LDIM*8;                 // 262144
  const size_t perBatchFloats = 2*PB_PART + 14*(size_t)LDIM + 3*(size_t)LDIM*DDIM;
  const size_t perBatchBytes = perBatchFloats * sizeof(float);
  int nbMax = (int)(ws_size / perBatchBytes);
  if (nbMax < 1) nbMax = 1;
  if (nbMax > BDIM) nbMax = BDIM;

  for (int b0 = 0; b0 < BDIM; b0 += nbMax) {
    const int nb = (BDIM - b0 < nbMax) ? (BDIM - b0) : nbMax;
    float* rowPart = (float*)d_ws;
    float* colPart = rowPart + (size_t)nb*PB_PART;
    float* rowW = colPart + (size_t)nb*PB_PART;
    int*   rowI = (int*)(rowW + (size_t)nb*LDIM*3);
    float* rowS = (float*)(rowI + (size_t)nb*LDIM*3);
    float* colW = rowS + (size_t)nb*LDIM;
    int*   colI = (int*)(colW + (size_t)nb*LDIM*3);
    float* colS = (float*)(colI + (size_t)nb*LDIM*3);
    float* attC = colS + (size_t)nb*LDIM;
    float* outC = attC + (size_t)nb*LDIM*DDIM;
    float* outM = outC + (size_t)nb*LDIM*DDIM;
    const float* ctxb = ctx + (size_t)b0*LDIM*DDIM;
    const float* mnb  = mn  + (size_t)b0*LDIM*DDIM;

    gemm_fused<<<dim3(NBLK, NBLK, nb), 256, 0, stream>>>(ctxb, mnb, rowPart, colPart);
    reduce_stats<<<dim3(nb*8), 256, 0, stream>>>(rowPart, rowW, rowI, rowS);
    reduce_stats<<<dim3(nb*8), 256, 0, stream>>>(colPart, colW, colI, colS);
    hipMemsetAsync(attC, 0, (size_t)nb*LDIM*DDIM*sizeof(float), stream);
    scatter_att<<<dim3(LDIM, nb), 128, 0, stream>>>(ctxb, rowW, rowI, attC);
    make_outputs<<<dim3(LDIM, nb), 128, 0, stream>>>(ctxb, mnb, attC, rowS, colW, colI, colS, outC, outM);
    conv_pool<<<dim3((LDIM - 2 + TCONV - 1)/TCONV, nb, 2), 128, 0, stream>>>(
        outC, outM, wconv, bias, out + (size_t)b0*2*FDIM);
  }
}